// Round 5
// baseline (483.595 us; speedup 1.0000x reference)
//
#include <hip/hip_runtime.h>
#include <hip/hip_bf16.h>
#include <stdint.h>

#define NQ 128
#define NLVL 5

typedef float  floatx4 __attribute__((ext_vector_type(4)));
typedef short  short8  __attribute__((ext_vector_type(8)));

__device__ __forceinline__ uint16_t f2bf(float f) {
    uint32_t u = __builtin_bit_cast(uint32_t, f);
    uint32_t r = u + 0x7FFFu + ((u >> 16) & 1u);   // round-to-nearest-even
    return (uint16_t)(r >> 16);
}
__device__ __forceinline__ uint32_t pack2(float a, float b) {
    return (uint32_t)f2bf(a) | ((uint32_t)f2bf(b) << 16);
}
__device__ __forceinline__ float bf2f(uint16_t u) {
    return __builtin_bit_cast(float, (uint32_t)u << 16);
}
__device__ __forceinline__ short8 cvt8(float4 lo, float4 hi) {
    union { short8 s; uint32_t u[4]; } r;
    r.u[0] = pack2(lo.x, lo.y);
    r.u[1] = pack2(lo.z, lo.w);
    r.u[2] = pack2(hi.x, hi.y);
    r.u[3] = pack2(hi.z, hi.w);
    return r.s;
}
// hi/lo bf16 split of 8 fp32 (for fp32-accurate MFMA via two bf16 MFMAs)
__device__ __forceinline__ void split_hilo(float4 v0, float4 v1, short8& hi, short8& lo) {
    hi = cvt8(v0, v1);
    float4 r0, r1;
    r0.x = v0.x - bf2f((uint16_t)hi[0]); r0.y = v0.y - bf2f((uint16_t)hi[1]);
    r0.z = v0.z - bf2f((uint16_t)hi[2]); r0.w = v0.w - bf2f((uint16_t)hi[3]);
    r1.x = v1.x - bf2f((uint16_t)hi[4]); r1.y = v1.y - bf2f((uint16_t)hi[5]);
    r1.z = v1.z - bf2f((uint16_t)hi[6]); r1.w = v1.w - bf2f((uint16_t)hi[7]);
    lo = cvt8(r0, r1);
}

#define MFMA16(a, b, c) __builtin_amdgcn_mfma_f32_16x16x32_bf16((a), (b), (c), 0, 0, 0)

// =================================================================== A ======
// Fused: gram (levels 0/1, direct-from-global MFMA, barrier-free) + softmax.
// Gram: G(n,c,c') = sum_h x[n][c][h] x[n][c'][h].  A-frag and B-frag of the
// 16x16x32 MFMA have identical lane->(row,k) layout, and k (=h) is contiguous
// in memory -> load fragments straight to registers; no LDS, no syncthreads.

struct AParams {
    const float* x0; const float* x1;
    float*       g0; float*       g1;
    const float* w[NLVL];
    uint16_t*    smT[NLVL];
    int          C[NLVL];
};

// diagonal 64x64 tile: A-rows == B-rows, af == fr.  Manual 2-deep pipeline.
__device__ __forceinline__ void gram_tile_diag(
    const float* __restrict__ base, int ldr, int k0, int nst,
    int m, int kg, floatx4 (&acc)[4][4])
{
    float4 Alo[4], Ahi[4], Blo[4], Bhi[4];
    {
        int k = k0 + kg * 8;
        #pragma unroll
        for (int f = 0; f < 4; ++f) {
            const float* q = base + (size_t)(f * 16 + m) * ldr + k;
            Alo[f] = *(const float4*)q; Ahi[f] = *(const float4*)(q + 4);
        }
    }
    for (int s = 0; s < nst; s += 2) {          // nst is even (16 / 64)
        if (s + 1 < nst) {
            int k1 = k0 + (s + 1) * 32 + kg * 8;
            #pragma unroll
            for (int f = 0; f < 4; ++f) {
                const float* q = base + (size_t)(f * 16 + m) * ldr + k1;
                Blo[f] = *(const float4*)q; Bhi[f] = *(const float4*)(q + 4);
            }
        }
        {
            short8 fr[4];
            #pragma unroll
            for (int f = 0; f < 4; ++f) fr[f] = cvt8(Alo[f], Ahi[f]);
            #pragma unroll
            for (int rf = 0; rf < 4; ++rf)
                #pragma unroll
                for (int cf = 0; cf < 4; ++cf)
                    acc[rf][cf] = MFMA16(fr[rf], fr[cf], acc[rf][cf]);
        }
        if (s + 2 < nst) {
            int k2 = k0 + (s + 2) * 32 + kg * 8;
            #pragma unroll
            for (int f = 0; f < 4; ++f) {
                const float* q = base + (size_t)(f * 16 + m) * ldr + k2;
                Alo[f] = *(const float4*)q; Ahi[f] = *(const float4*)(q + 4);
            }
        }
        if (s + 1 < nst) {
            short8 fr[4];
            #pragma unroll
            for (int f = 0; f < 4; ++f) fr[f] = cvt8(Blo[f], Bhi[f]);
            #pragma unroll
            for (int rf = 0; rf < 4; ++rf)
                #pragma unroll
                for (int cf = 0; cf < 4; ++cf)
                    acc[rf][cf] = MFMA16(fr[rf], fr[cf], acc[rf][cf]);
        }
    }
}

// off-diagonal 64x64 tile (L1): A-rows != B-rows.  Reads overlap the block's
// diagonal waves -> L1/L2-hot; plain loop, compiler-scheduled.
__device__ __forceinline__ void gram_tile_off(
    const float* __restrict__ ab, const float* __restrict__ bb,
    int ldr, int k0, int nst, int m, int kg, floatx4 (&acc)[4][4])
{
    #pragma unroll 2
    for (int s = 0; s < nst; ++s) {
        int k = k0 + s * 32 + kg * 8;
        float4 a0[4], a1[4], b0[4], b1[4];
        #pragma unroll
        for (int f = 0; f < 4; ++f) {
            const float* qa = ab + (size_t)(f * 16 + m) * ldr + k;
            const float* qb = bb + (size_t)(f * 16 + m) * ldr + k;
            a0[f] = *(const float4*)qa; a1[f] = *(const float4*)(qa + 4);
            b0[f] = *(const float4*)qb; b1[f] = *(const float4*)(qb + 4);
        }
        short8 af[4], bf[4];
        #pragma unroll
        for (int f = 0; f < 4; ++f) {
            af[f] = cvt8(a0[f], a1[f]);
            bf[f] = cvt8(b0[f], b1[f]);
        }
        #pragma unroll
        for (int rf = 0; rf < 4; ++rf)
            #pragma unroll
            for (int cf = 0; cf < 4; ++cf)
                acc[rf][cf] = MFMA16(af[rf], bf[cf], acc[rf][cf]);
    }
}

__global__ __launch_bounds__(256) void gram_sm_kernel(AParams p) {
    __shared__ float gred[4096];
    int b  = blockIdx.x;
    int t  = threadIdx.x;
    int wv = t >> 6, lane = t & 63, m = lane & 15, kg = lane >> 4;

    if (b >= 320) {                 // ---------------- softmax (160 blocks) --
        int idx = (b - 320) * 4 + wv;       // 640 (lvl,o) pairs, one per wave
        int lvl = idx >> 7, o = idx & 127;
        int C   = p.C[lvl];
        const float* w = p.w[lvl];
        float ev[8];
        int nIter = C >> 6;
        float mx = -1e30f;
        for (int it = 0; it < nIter; ++it) {
            float z = 10.0f * w[(size_t)(it * 64 + lane) * NQ + o];
            ev[it] = z;
            mx = fmaxf(mx, z);
        }
        #pragma unroll
        for (int s = 32; s; s >>= 1) mx = fmaxf(mx, __shfl_xor(mx, s));
        float sum = 0.f;
        for (int it = 0; it < nIter; ++it) { ev[it] = expf(ev[it] - mx); sum += ev[it]; }
        #pragma unroll
        for (int s = 32; s; s >>= 1) sum += __shfl_xor(sum, s);
        float inv = 1.0f / sum;
        uint16_t* dst = p.smT[lvl] + (size_t)o * C;
        for (int it = 0; it < nIter; ++it) dst[it * 64 + lane] = f2bf(ev[it] * inv);
        return;
    }

    floatx4 acc[4][4];
    floatx4 zero = {0.f, 0.f, 0.f, 0.f};
    #pragma unroll
    for (int i = 0; i < 4; ++i)
        #pragma unroll
        for (int j = 0; j < 4; ++j) acc[i][j] = zero;

    if (b < 256) {                  // ---------- level 0 (C=64, HW=65536) ----
        int n = b >> 5, ch = b & 31;        // 32 chunks of 2048 h; wave: 512 h
        const float* xb = p.x0 + (size_t)n * 64 * 65536;
        int k0 = ch * 2048 + wv * 512;
        gram_tile_diag(xb, 65536, k0, 16, m, kg, acc);

        // 4 waves -> one tile via LDS, then one atomic set per block
        for (int i = t; i < 4096; i += 256) gred[i] = 0.f;
        __syncthreads();
        #pragma unroll
        for (int rf = 0; rf < 4; ++rf)
            #pragma unroll
            for (int cf = 0; cf < 4; ++cf)
                #pragma unroll
                for (int r = 0; r < 4; ++r)
                    atomicAdd(&gred[(rf * 16 + kg * 4 + r) * 64 + cf * 16 + m],
                              acc[rf][cf][r]);
        __syncthreads();
        float* gb = p.g0 + (size_t)n * 4096;
        for (int i = t; i < 4096; i += 256) atomicAdd(&gb[i], gred[i]);
    } else {                        // ---------- level 1 (C=128, HW=16384) ---
        int b2 = b - 256;                   // 64 blocks: 8 kchunks of 2048 h
        int n = b2 >> 3, kc = b2 & 7;
        const float* xb = p.x1 + (size_t)n * 128 * 16384;
        int rb = wv >> 1, cb = wv & 1;      // wave = 64x64 subtile (rb,cb)
        const float* ab = xb + (size_t)rb * 64 * 16384;
        const float* bb = xb + (size_t)cb * 64 * 16384;
        int k0 = kc * 2048;
        if (rb == cb) gram_tile_diag(ab, 16384, k0, 64, m, kg, acc);
        else          gram_tile_off(ab, bb, 16384, k0, 64, m, kg, acc);
        float* gb = p.g1 + (size_t)n * 16384;
        #pragma unroll
        for (int rf = 0; rf < 4; ++rf)
            #pragma unroll
            for (int cf = 0; cf < 4; ++cf)
                #pragma unroll
                for (int r = 0; r < 4; ++r)
                    atomicAdd(&gb[(size_t)(rb * 64 + rf * 16 + kg * 4 + r) * 128 +
                                  cb * 64 + cf * 16 + m],
                              acc[rf][cf][r]);
    }
}

// =================================================================== B ======
// Fused: quad (levels 2-4, LDS-staged MFMA) + sgs (levels 0/1 from G).
// sgs reads G fragments DIRECT from global (L2-hot) with in-register hi/lo
// bf16 split -> no LDS, so it doesn't cap quad occupancy.

struct QSParams {
    const float*    x[3];          // levels 2,3,4
    const uint16_t* smT[3];
    float*          quad;          // padded stride 16 floats
    int             C[3];
    int             HW[3];
    int             blk_base[3];
    int             quad_blocks;   // 672
    const float*    g0; const float* g1;
    const uint16_t* smT0; const uint16_t* smT1;
};

template<int C>
__device__ __forceinline__ void sgs_direct(const float* __restrict__ g,
                                           const uint16_t* __restrict__ smT,
                                           float* __restrict__ qdst) {
    constexpr int RF  = C / 64;
    constexpr int KSL = C / 32;
    int t = threadIdx.x;
    int wv = t >> 6, lane = t & 63, m = lane & 15, kg = lane >> 4;
    floatx4 acc[RF][8];
    floatx4 zero = {0.f, 0.f, 0.f, 0.f};
    #pragma unroll
    for (int rf = 0; rf < RF; ++rf)
        #pragma unroll
        for (int ot = 0; ot < 8; ++ot) acc[rf][ot] = zero;

    #pragma unroll
    for (int ksl = 0; ksl < KSL; ++ksl) {
        short8 bfr[8];
        #pragma unroll
        for (int ot = 0; ot < 8; ++ot)
            bfr[ot] = *(const short8*)(smT + (size_t)(ot * 16 + m) * C + ksl * 32 + kg * 8);
        #pragma unroll
        for (int rf = 0; rf < RF; ++rf) {
            const float* gp = g + (size_t)((wv * RF + rf) * 16 + m) * C + ksl * 32 + kg * 8;
            float4 v0 = *(const float4*)gp, v1 = *(const float4*)(gp + 4);
            short8 ah, al;
            split_hilo(v0, v1, ah, al);
            #pragma unroll
            for (int ot = 0; ot < 8; ++ot) {
                acc[rf][ot] = MFMA16(ah, bfr[ot], acc[rf][ot]);
                acc[rf][ot] = MFMA16(al, bfr[ot], acc[rf][ot]);
            }
        }
    }
    #pragma unroll
    for (int ot = 0; ot < 8; ++ot) {
        float part = 0.f;
        #pragma unroll
        for (int rf = 0; rf < RF; ++rf) {
            int c0 = (wv * RF + rf) * 16 + kg * 4;
            #pragma unroll
            for (int r = 0; r < 4; ++r) {
                float sv = bf2f(smT[(size_t)(ot * 16 + m) * C + c0 + r]);
                part = fmaf(sv, acc[rf][ot][r], part);
            }
        }
        part += __shfl_xor(part, 16);
        part += __shfl_xor(part, 32);
        if (lane < 16) atomicAdd(qdst + (size_t)(ot * 16 + lane) * 16, part);
    }
}

__global__ __launch_bounds__(256) void quad_sgs_kernel(QSParams p) {
    __shared__ __align__(16) short At[64 * 40];
    __shared__ __align__(16) short Bt[128 * 40];

    int bid = blockIdx.x;
    if (bid >= p.quad_blocks) {     // ------------------- sgs (16 blocks) ----
        int b = bid - p.quad_blocks;
        int lvl = b >> 3, n = b & 7;
        if (lvl == 0)
            sgs_direct<64>(p.g0 + (size_t)n * 4096, p.smT0,
                           p.quad + (size_t)n * 2048);
        else
            sgs_direct<128>(p.g1 + (size_t)n * 16384, p.smT1,
                            p.quad + (size_t)(8 + n) * 2048);
        return;
    }

    // --------------------------- quad, levels 2-4 ---------------------------
    int lvl = 0;
    #pragma unroll
    for (int l = 1; l < 3; ++l) if (bid >= p.blk_base[l]) lvl = l;
    int rel = bid - p.blk_base[lvl];
    int n   = rel & 7;
    int ht  = rel >> 3;
    int C   = p.C[lvl];
    int HW  = p.HW[lvl];
    int h0  = ht * 64;

    const float*    xb  = p.x[lvl] + (size_t)n * C * HW + h0;
    const uint16_t* smT = p.smT[lvl];

    int t    = threadIdx.x;
    int wave = t >> 6;
    int lane = t & 63;
    int m    = lane & 15;
    int kg   = lane >> 4;

    floatx4 acc[4][2];
    floatx4 zero = {0.f, 0.f, 0.f, 0.f};
    #pragma unroll
    for (int i = 0; i < 4; ++i)
        #pragma unroll
        for (int j = 0; j < 2; ++j) acc[i][j] = zero;

    int c_l = (t & 15) * 2;
    int h_l = (t >> 4) * 4;

    for (int c0 = 0; c0 < C; c0 += 32) {
        const float* s1 = xb + (size_t)(c0 + c_l) * HW + h_l;
        float4 a4 = *(const float4*)s1;
        float4 b4 = *(const float4*)(s1 + HW);
        #pragma unroll
        for (int j = 0; j < 4; ++j) {
            uint32_t pk = (uint32_t)f2bf(((const float*)&a4)[j]) |
                          ((uint32_t)f2bf(((const float*)&b4)[j]) << 16);
            *(uint32_t*)&At[(h_l + j) * 40 + c_l] = pk;
        }
        #pragma unroll
        for (int it = 0; it < 2; ++it) {
            int idx  = it * 256 + t;
            int o    = idx >> 2;
            int part = idx & 3;
            uint4 v = *(const uint4*)(smT + (size_t)o * C + c0 + part * 8);
            *(uint4*)&Bt[o * 40 + part * 8] = v;
        }
        __syncthreads();

        short8 af[4];
        #pragma unroll
        for (int mt = 0; mt < 4; ++mt)
            af[mt] = *(const short8*)&At[(mt * 16 + m) * 40 + kg * 8];
        short8 bfr[2];
        #pragma unroll
        for (int ot = 0; ot < 2; ++ot)
            bfr[ot] = *(const short8*)&Bt[((wave * 2 + ot) * 16 + m) * 40 + kg * 8];
        #pragma unroll
        for (int mt = 0; mt < 4; ++mt)
            #pragma unroll
            for (int ot = 0; ot < 2; ++ot)
                acc[mt][ot] = MFMA16(af[mt], bfr[ot], acc[mt][ot]);
        __syncthreads();
    }

    float* qbase = p.quad + (size_t)((lvl + 2) * 8 + n) * 128 * 16;
    #pragma unroll
    for (int ot = 0; ot < 2; ++ot) {
        float part = 0.f;
        #pragma unroll
        for (int mt = 0; mt < 4; ++mt)
            #pragma unroll
            for (int r = 0; r < 4; ++r) {
                float v = acc[mt][ot][r];
                part = fmaf(v, v, part);
            }
        part += __shfl_xor(part, 16);
        part += __shfl_xor(part, 32);
        if (lane < 16) {
            int o = (wave * 2 + ot) * 16 + lane;
            atomicAdd(qbase + (size_t)o * 16, part);
        }
    }
}

// ------------------------------------------------------------- head (split) --
__global__ __launch_bounds__(256) void hfc1_kernel(
    const float* __restrict__ quad, const float* __restrict__ w,
    const float* __restrict__ b, float* __restrict__ h1) {
    __shared__ float feat[640];
    __shared__ float stats[10];
    __shared__ float part[256];
    int blk = blockIdx.x;
    int n = blk >> 3, c8 = blk & 7;
    int t = threadIdx.x;
    for (int idx = t; idx < 640; idx += 256) {
        int L = idx >> 7, o = idx & 127;
        feat[idx] = quad[((size_t)(L * 8 + n) * 128 + o) * 16];
    }
    __syncthreads();
    int wv = t >> 6, lane = t & 63;
    for (int L = wv; L < 5; L += 4) {
        float a = feat[L * 128 + lane], c = feat[L * 128 + 64 + lane];
        float s = a + c;
        #pragma unroll
        for (int sh = 32; sh; sh >>= 1) s += __shfl_xor(s, sh);
        float mean = s * (1.f / 128.f);
        float d0 = a - mean, d1 = c - mean;
        float v = d0 * d0 + d1 * d1;
        #pragma unroll
        for (int sh = 32; sh; sh >>= 1) v += __shfl_xor(v, sh);
        if (lane == 0) {
            stats[L]     = mean;
            stats[5 + L] = 1.f / (sqrtf(v * (1.f / 127.f)) + 1e-8f);
        }
    }
    __syncthreads();
    for (int idx = t; idx < 640; idx += 256) {
        int L = idx >> 7;
        feat[idx] = (feat[idx] - stats[L]) * stats[5 + L];
    }
    __syncthreads();

    float acc = 0.f;
    const float* wc = w + c8 * 64 + lane;
    int k0 = wv * 160;
    #pragma unroll 8
    for (int k = k0; k < k0 + 160; ++k) acc = fmaf(feat[k], wc[(size_t)k * 512], acc);
    part[t] = acc;
    __syncthreads();
    if (t < 64) {
        float r = part[t] + part[t + 64] + part[t + 128] + part[t + 192];
        h1[(size_t)n * 512 + c8 * 64 + t] = r + b[c8 * 64 + t];
    }
}

__device__ __forceinline__ void norm_leaky_512(float* buf, float* red, int t) {
    float a = buf[t], c = buf[t + 256];
    float s = a + c;
    #pragma unroll
    for (int sh = 32; sh; sh >>= 1) s += __shfl_xor(s, sh);
    if ((t & 63) == 0) red[t >> 6] = s;
    __syncthreads();
    float mean = (red[0] + red[1] + red[2] + red[3]) * (1.f / 512.f);
    float d0 = a - mean, d1 = c - mean;
    float v = d0 * d0 + d1 * d1;
    #pragma unroll
    for (int sh = 32; sh; sh >>= 1) v += __shfl_xor(v, sh);
    __syncthreads();
    if ((t & 63) == 0) red[t >> 6] = v;
    __syncthreads();
    float inv = 1.f / (sqrtf((red[0] + red[1] + red[2] + red[3]) * (1.f / 511.f)) + 1e-8f);
    float n0 = d0 * inv, n1 = d1 * inv;
    buf[t]       = n0 > 0.f ? n0 : 0.01f * n0;
    buf[t + 256] = n1 > 0.f ? n1 : 0.01f * n1;
    __syncthreads();
}

__global__ __launch_bounds__(256) void hfc2_kernel(
    const float* __restrict__ h1, const float* __restrict__ w,
    const float* __restrict__ b, float* __restrict__ h2) {
    __shared__ float buf[512];
    __shared__ float red[4];
    __shared__ float part[256];
    int blk = blockIdx.x;
    int n = blk >> 3, c8 = blk & 7;
    int t = threadIdx.x;
    buf[t]       = h1[(size_t)n * 512 + t];
    buf[t + 256] = h1[(size_t)n * 512 + t + 256];
    __syncthreads();
    norm_leaky_512(buf, red, t);
    int wv = t >> 6, lane = t & 63;
    float acc = 0.f;
    const float* wc = w + c8 * 64 + lane;
    int k0 = wv * 128;
    #pragma unroll 8
    for (int k = k0; k < k0 + 128; ++k) acc = fmaf(buf[k], wc[(size_t)k * 512], acc);
    part[t] = acc;
    __syncthreads();
    if (t < 64) {
        float r = part[t] + part[t + 64] + part[t + 128] + part[t + 192];
        h2[(size_t)n * 512 + c8 * 64 + t] = r + b[c8 * 64 + t];
    }
}

__global__ __launch_bounds__(256) void hfc3_kernel(
    const float* __restrict__ h2, const float* __restrict__ w,
    const float* __restrict__ b, float* __restrict__ out) {
    __shared__ float buf[512];
    __shared__ float red[4];
    __shared__ float part[256];
    int blk = blockIdx.x;
    int n = blk >> 1, c2 = blk & 1;
    int t = threadIdx.x;
    buf[t]       = h2[(size_t)n * 512 + t];
    buf[t + 256] = h2[(size_t)n * 512 + t + 256];
    __syncthreads();
    norm_leaky_512(buf, red, t);
    int wv = t >> 6, lane = t & 63;
    float acc = 0.f;
    const float* wc = w + c2 * 64 + lane;
    int k0 = wv * 128;
    #pragma unroll 8
    for (int k = k0; k < k0 + 128; ++k) acc = fmaf(buf[k], wc[(size_t)k * 128], acc);
    part[t] = acc;
    __syncthreads();
    if (t < 64) {
        out[(size_t)n * 128 + c2 * 64 + t] =
            part[t] + part[t + 64] + part[t + 128] + part[t + 192] + b[c2 * 64 + t];
    }
}

// ----------------------------------------------------------------- launch ----
extern "C" void kernel_launch(void* const* d_in, const int* in_sizes, int n_in,
                              void* d_out, int out_size, void* d_ws, size_t ws_size,
                              hipStream_t stream) {
    static const int Cs[NLVL]   = {64, 128, 256, 512, 512};
    static const int RESs[NLVL] = {256, 128, 64, 32, 16};

    const float* x[NLVL];
    const float* w[NLVL];
    for (int i = 0; i < NLVL; ++i) {
        x[i] = (const float*)d_in[2 * i];
        w[i] = (const float*)d_in[2 * i + 1];
    }
    const float* fc1_w = (const float*)d_in[10];
    const float* fc1_b = (const float*)d_in[11];
    const float* fc2_w = (const float*)d_in[12];
    const float* fc2_b = (const float*)d_in[13];
    const float* fc3_w = (const float*)d_in[14];
    const float* fc3_b = (const float*)d_in[15];

    // workspace: smT (bf16) | quad padded fp32 | G0 | G1 | h1 | h2
    uint16_t* smT_base = (uint16_t*)d_ws;
    int smOff[NLVL];
    int off = 0;
    for (int i = 0; i < NLVL; ++i) { smOff[i] = off; off += Cs[i] * NQ; }
    size_t smBytes = (size_t)off * sizeof(uint16_t);
    float* quad = (float*)((char*)d_ws + smBytes);
    size_t quadFloats = (size_t)NLVL * 8 * NQ * 16;
    float* g0 = quad + quadFloats;
    float* g1 = g0 + (size_t)8 * 64 * 64;
    float* h1 = g1 + (size_t)8 * 128 * 128;
    float* h2 = h1 + (size_t)8 * 512;
    size_t zeroBytes = (quadFloats + (size_t)8 * 64 * 64 + (size_t)8 * 128 * 128) * sizeof(float);

    hipMemsetAsync(quad, 0, zeroBytes, stream);

    AParams ap;
    ap.x0 = x[0]; ap.x1 = x[1]; ap.g0 = g0; ap.g1 = g1;
    for (int i = 0; i < NLVL; ++i) {
        ap.w[i]   = w[i];
        ap.smT[i] = smT_base + smOff[i];
        ap.C[i]   = Cs[i];
    }
    // blocks: 256 L0-gram + 64 L1-gram + 160 softmax (4 (lvl,o)/block)
    gram_sm_kernel<<<480, 256, 0, stream>>>(ap);

    QSParams qp;
    int base = 0;
    for (int i = 0; i < 3; ++i) {
        int lvl = i + 2;
        qp.x[i]   = x[lvl];
        qp.smT[i] = smT_base + smOff[lvl];
        qp.C[i]   = Cs[lvl];
        qp.HW[i]  = RESs[lvl] * RESs[lvl];
        qp.blk_base[i] = base;
        base += (RESs[lvl] * RESs[lvl] / 64) * 8;
    }
    qp.quad = quad;
    qp.quad_blocks = base;                   // 672
    qp.g0 = g0; qp.g1 = g1;
    qp.smT0 = smT_base + smOff[0];
    qp.smT1 = smT_base + smOff[1];
    quad_sgs_kernel<<<base + 16, 256, 0, stream>>>(qp);

    hfc1_kernel<<<64, 256, 0, stream>>>(quad, fc1_w, fc1_b, h1);
    hfc2_kernel<<<64, 256, 0, stream>>>(h1, fc2_w, fc2_b, h2);
    hfc3_kernel<<<16, 256, 0, stream>>>(h2, fc3_w, fc3_b, (float*)d_out);
}

// Round 6
// 423.942 us; speedup vs baseline: 1.1407x; 1.1407x over previous
//
#include <hip/hip_runtime.h>
#include <hip/hip_bf16.h>
#include <stdint.h>

#define NQ 128
#define NLVL 5

typedef float  floatx4 __attribute__((ext_vector_type(4)));
typedef short  short8  __attribute__((ext_vector_type(8)));

__device__ __forceinline__ uint16_t f2bf(float f) {
    uint32_t u = __builtin_bit_cast(uint32_t, f);
    uint32_t r = u + 0x7FFFu + ((u >> 16) & 1u);   // round-to-nearest-even
    return (uint16_t)(r >> 16);
}
__device__ __forceinline__ uint32_t pack2(float a, float b) {
    return (uint32_t)f2bf(a) | ((uint32_t)f2bf(b) << 16);
}
__device__ __forceinline__ float bf2f(uint16_t u) {
    return __builtin_bit_cast(float, (uint32_t)u << 16);
}
__device__ __forceinline__ short8 cvt8(float4 lo, float4 hi) {
    union { short8 s; uint32_t u[4]; } r;
    r.u[0] = pack2(lo.x, lo.y);
    r.u[1] = pack2(lo.z, lo.w);
    r.u[2] = pack2(hi.x, hi.y);
    r.u[3] = pack2(hi.z, hi.w);
    return r.s;
}
__device__ __forceinline__ void split_hilo(float4 v0, float4 v1, short8& hi, short8& lo) {
    hi = cvt8(v0, v1);
    float4 r0, r1;
    r0.x = v0.x - bf2f((uint16_t)hi[0]); r0.y = v0.y - bf2f((uint16_t)hi[1]);
    r0.z = v0.z - bf2f((uint16_t)hi[2]); r0.w = v0.w - bf2f((uint16_t)hi[3]);
    r1.x = v1.x - bf2f((uint16_t)hi[4]); r1.y = v1.y - bf2f((uint16_t)hi[5]);
    r1.z = v1.z - bf2f((uint16_t)hi[6]); r1.w = v1.w - bf2f((uint16_t)hi[7]);
    lo = cvt8(r0, r1);
}

#define MFMA16(a, b, c) __builtin_amdgcn_mfma_f32_16x16x32_bf16((a), (b), (c), 0, 0, 0)

// =================================================================== A ======
// Fused gram (levels 0/1, LDS-staged MFMA, 512-thread / 8-wave blocks for
// residency) + softmax.  Same block count & atomic count as the proven 97us
// version; 2x the waves per CU (occupancy was the limiter, not bandwidth).

struct AParams {
    const float* x0; const float* x1;
    float*       g0; float*       g1;
    const float* w[NLVL];
    uint16_t*    smT[NLVL];
    int          C[NLVL];
};

__global__ __launch_bounds__(512, 5) void gram_sm_kernel(AParams p) {
    // L0: two 64x(64+8)-short buffers (one per split-K half). L1: one 128x72.
    __shared__ __align__(16) short lds[2 * 64 * 72];   // 18,432 B
    int b = blockIdx.x;
    int t = threadIdx.x;
    int wv = t >> 6, lane = t & 63, m = lane & 15, kg = lane >> 4;

    if (b >= 768) {                 // ---------------- softmax (80 blocks) ---
        int idx = (b - 768) * 8 + wv;       // 640 (lvl,o) pairs, one per wave
        int lvl = idx >> 7, o = idx & 127;
        int C   = p.C[lvl];
        const float* w = p.w[lvl];
        float ev[8];
        int nIter = C >> 6;
        float mx = -1e30f;
        for (int it = 0; it < nIter; ++it) {
            float z = 10.0f * w[(size_t)(it * 64 + lane) * NQ + o];
            ev[it] = z;
            mx = fmaxf(mx, z);
        }
        #pragma unroll
        for (int s = 32; s; s >>= 1) mx = fmaxf(mx, __shfl_xor(mx, s));
        float sum = 0.f;
        for (int it = 0; it < nIter; ++it) { ev[it] = expf(ev[it] - mx); sum += ev[it]; }
        #pragma unroll
        for (int s = 32; s; s >>= 1) sum += __shfl_xor(sum, s);
        float inv = 1.0f / sum;
        uint16_t* dst = p.smT[lvl] + (size_t)o * C;
        for (int it = 0; it < nIter; ++it) dst[it * 64 + lane] = f2bf(ev[it] * inv);
        return;
    }

    if (b < 512) {                  // ---------- level 0 (C=64, HW=65536) ----
        // block = (n, 1024-h chunk); wave (rg, kh): rows rg*16..+16,
        // split-K half kh (512 h, 8 steps of 64).  LDS reduce -> 1 atomic set.
        int n = b >> 6, ch = b & 63;
        const float* xb = p.x0 + (size_t)n * 64 * 65536;
        int rg = wv & 3, kh = wv >> 2;
        short* buf = lds + kh * (64 * 72);
        int tg = t & 255;                   // staging group = 4 waves (kh)
        int k0 = ch * 1024 + kh * 512;

        floatx4 acc[4];
        floatx4 zero = {0.f, 0.f, 0.f, 0.f};
        #pragma unroll
        for (int cf = 0; cf < 4; ++cf) acc[cf] = zero;

        float4 v[4];
        #pragma unroll
        for (int j = 0; j < 4; ++j) {       // prologue: load step 0
            int fid = j * 256 + tg;
            v[j] = *(const float4*)(xb + (size_t)(fid >> 4) * 65536 + k0 + (fid & 15) * 4);
        }
        for (int s = 0; s < 8; ++s) {
            __syncthreads();                // prior step's frag reads done
            #pragma unroll
            for (int j = 0; j < 4; ++j) {
                int fid = j * 256 + tg;
                uint2 pk = { pack2(v[j].x, v[j].y), pack2(v[j].z, v[j].w) };
                *(uint2*)&buf[(fid >> 4) * 72 + (fid & 15) * 4] = pk;
            }
            __syncthreads();                // writes visible
            if (s + 1 < 8) {                // in flight during frag+MFMA
                #pragma unroll
                for (int j = 0; j < 4; ++j) {
                    int fid = j * 256 + tg;
                    v[j] = *(const float4*)(xb + (size_t)(fid >> 4) * 65536 +
                                            k0 + (s + 1) * 64 + (fid & 15) * 4);
                }
            }
            #pragma unroll
            for (int ksl = 0; ksl < 2; ++ksl) {
                short8 fr[4];
                #pragma unroll
                for (int f = 0; f < 4; ++f)
                    fr[f] = *(const short8*)&buf[(f * 16 + m) * 72 + ksl * 32 + kg * 8];
                short8 a = fr[rg];
                #pragma unroll
                for (int cf = 0; cf < 4; ++cf)
                    acc[cf] = MFMA16(a, fr[cf], acc[cf]);
            }
        }
        // reduce the two kh-halves in LDS, then one atomic per entry
        __syncthreads();
        float* gred = (float*)lds;          // 16,384 B <= 18,432
        for (int i = t; i < 4096; i += 512) gred[i] = 0.f;
        __syncthreads();
        #pragma unroll
        for (int cf = 0; cf < 4; ++cf)
            #pragma unroll
            for (int r = 0; r < 4; ++r)
                atomicAdd(&gred[(rg * 16 + kg * 4 + r) * 64 + cf * 16 + m], acc[cf][r]);
        __syncthreads();
        float* gb = p.g0 + (size_t)n * 4096;
        for (int i = t; i < 4096; i += 512) atomicAdd(&gb[i], gred[i]);
    } else {                        // ---------- level 1 (C=128, HW=16384) ---
        // block = (n, 512-h chunk); wave (rg, cg): 32 rows x 64 cols subtile.
        int b2 = b - 512;
        int n = b2 >> 5, ch = b2 & 31;
        const float* xb = p.x1 + (size_t)n * 128 * 16384;
        int rg = wv & 3, cg = wv >> 2;
        int k0 = ch * 512;

        floatx4 acc[2][4];
        floatx4 zero = {0.f, 0.f, 0.f, 0.f};
        #pragma unroll
        for (int rf = 0; rf < 2; ++rf)
            #pragma unroll
            for (int cf = 0; cf < 4; ++cf) acc[rf][cf] = zero;

        float4 v[4];
        #pragma unroll
        for (int j = 0; j < 4; ++j) {
            int fid = j * 512 + t;
            v[j] = *(const float4*)(xb + (size_t)(fid >> 4) * 16384 + k0 + (fid & 15) * 4);
        }
        for (int s = 0; s < 8; ++s) {
            __syncthreads();
            #pragma unroll
            for (int j = 0; j < 4; ++j) {
                int fid = j * 512 + t;
                uint2 pk = { pack2(v[j].x, v[j].y), pack2(v[j].z, v[j].w) };
                *(uint2*)&lds[(fid >> 4) * 72 + (fid & 15) * 4] = pk;
            }
            __syncthreads();
            if (s + 1 < 8) {
                #pragma unroll
                for (int j = 0; j < 4; ++j) {
                    int fid = j * 512 + t;
                    v[j] = *(const float4*)(xb + (size_t)(fid >> 4) * 16384 +
                                            k0 + (s + 1) * 64 + (fid & 15) * 4);
                }
            }
            #pragma unroll
            for (int ksl = 0; ksl < 2; ++ksl) {
                short8 af[2], bf[4];
                #pragma unroll
                for (int rf = 0; rf < 2; ++rf)
                    af[rf] = *(const short8*)&lds[(rg * 32 + rf * 16 + m) * 72 + ksl * 32 + kg * 8];
                #pragma unroll
                for (int cf = 0; cf < 4; ++cf)
                    bf[cf] = *(const short8*)&lds[(cg * 64 + cf * 16 + m) * 72 + ksl * 32 + kg * 8];
                #pragma unroll
                for (int rf = 0; rf < 2; ++rf)
                    #pragma unroll
                    for (int cf = 0; cf < 4; ++cf)
                        acc[rf][cf] = MFMA16(af[rf], bf[cf], acc[rf][cf]);
            }
        }
        float* gb = p.g1 + (size_t)n * 16384;
        #pragma unroll
        for (int rf = 0; rf < 2; ++rf)
            #pragma unroll
            for (int cf = 0; cf < 4; ++cf)
                #pragma unroll
                for (int r = 0; r < 4; ++r)
                    atomicAdd(&gb[(size_t)(rg * 32 + rf * 16 + kg * 4 + r) * 128 +
                                  cg * 64 + cf * 16 + m],
                              acc[rf][cf][r]);
    }
}

// =================================================================== B ======
// Fused: quad (levels 2-4, LDS-staged MFMA) + sgs (levels 0/1 from G, direct
// global reads with in-register hi/lo bf16 split).

struct QSParams {
    const float*    x[3];          // levels 2,3,4
    const uint16_t* smT[3];
    float*          quad;          // padded stride 16 floats
    int             C[3];
    int             HW[3];
    int             blk_base[3];
    int             quad_blocks;   // 672
    const float*    g0; const float* g1;
    const uint16_t* smT0; const uint16_t* smT1;
};

template<int C>
__device__ __forceinline__ void sgs_direct(const float* __restrict__ g,
                                           const uint16_t* __restrict__ smT,
                                           float* __restrict__ qdst) {
    constexpr int RF  = C / 64;
    constexpr int KSL = C / 32;
    int t = threadIdx.x;
    int wv = t >> 6, lane = t & 63, m = lane & 15, kg = lane >> 4;
    floatx4 acc[RF][8];
    floatx4 zero = {0.f, 0.f, 0.f, 0.f};
    #pragma unroll
    for (int rf = 0; rf < RF; ++rf)
        #pragma unroll
        for (int ot = 0; ot < 8; ++ot) acc[rf][ot] = zero;

    #pragma unroll
    for (int ksl = 0; ksl < KSL; ++ksl) {
        short8 bfr[8];
        #pragma unroll
        for (int ot = 0; ot < 8; ++ot)
            bfr[ot] = *(const short8*)(smT + (size_t)(ot * 16 + m) * C + ksl * 32 + kg * 8);
        #pragma unroll
        for (int rf = 0; rf < RF; ++rf) {
            const float* gp = g + (size_t)((wv * RF + rf) * 16 + m) * C + ksl * 32 + kg * 8;
            float4 v0 = *(const float4*)gp, v1 = *(const float4*)(gp + 4);
            short8 ah, al;
            split_hilo(v0, v1, ah, al);
            #pragma unroll
            for (int ot = 0; ot < 8; ++ot) {
                acc[rf][ot] = MFMA16(ah, bfr[ot], acc[rf][ot]);
                acc[rf][ot] = MFMA16(al, bfr[ot], acc[rf][ot]);
            }
        }
    }
    #pragma unroll
    for (int ot = 0; ot < 8; ++ot) {
        float part = 0.f;
        #pragma unroll
        for (int rf = 0; rf < RF; ++rf) {
            int c0 = (wv * RF + rf) * 16 + kg * 4;
            #pragma unroll
            for (int r = 0; r < 4; ++r) {
                float sv = bf2f(smT[(size_t)(ot * 16 + m) * C + c0 + r]);
                part = fmaf(sv, acc[rf][ot][r], part);
            }
        }
        part += __shfl_xor(part, 16);
        part += __shfl_xor(part, 32);
        if (lane < 16) atomicAdd(qdst + (size_t)(ot * 16 + lane) * 16, part);
    }
}

__global__ __launch_bounds__(256) void quad_sgs_kernel(QSParams p) {
    __shared__ __align__(16) short At[64 * 40];
    __shared__ __align__(16) short Bt[128 * 40];

    int bid = blockIdx.x;
    if (bid >= p.quad_blocks) {     // ------------------- sgs (16 blocks) ----
        int b = bid - p.quad_blocks;
        int lvl = b >> 3, n = b & 7;
        if (lvl == 0)
            sgs_direct<64>(p.g0 + (size_t)n * 4096, p.smT0,
                           p.quad + (size_t)n * 2048);
        else
            sgs_direct<128>(p.g1 + (size_t)n * 16384, p.smT1,
                            p.quad + (size_t)(8 + n) * 2048);
        return;
    }

    // --------------------------- quad, levels 2-4 ---------------------------
    int lvl = 0;
    #pragma unroll
    for (int l = 1; l < 3; ++l) if (bid >= p.blk_base[l]) lvl = l;
    int rel = bid - p.blk_base[lvl];
    int n   = rel & 7;
    int ht  = rel >> 3;
    int C   = p.C[lvl];
    int HW  = p.HW[lvl];
    int h0  = ht * 64;

    const float*    xb  = p.x[lvl] + (size_t)n * C * HW + h0;
    const uint16_t* smT = p.smT[lvl];

    int t    = threadIdx.x;
    int wave = t >> 6;
    int lane = t & 63;
    int m    = lane & 15;
    int kg   = lane >> 4;

    floatx4 acc[4][2];
    floatx4 zero = {0.f, 0.f, 0.f, 0.f};
    #pragma unroll
    for (int i = 0; i < 4; ++i)
        #pragma unroll
        for (int j = 0; j < 2; ++j) acc[i][j] = zero;

    int c_l = (t & 15) * 2;
    int h_l = (t >> 4) * 4;

    for (int c0 = 0; c0 < C; c0 += 32) {
        const float* s1 = xb + (size_t)(c0 + c_l) * HW + h_l;
        float4 a4 = *(const float4*)s1;
        float4 b4 = *(const float4*)(s1 + HW);
        #pragma unroll
        for (int j = 0; j < 4; ++j) {
            uint32_t pk = (uint32_t)f2bf(((const float*)&a4)[j]) |
                          ((uint32_t)f2bf(((const float*)&b4)[j]) << 16);
            *(uint32_t*)&At[(h_l + j) * 40 + c_l] = pk;
        }
        #pragma unroll
        for (int it = 0; it < 2; ++it) {
            int idx  = it * 256 + t;
            int o    = idx >> 2;
            int part = idx & 3;
            uint4 v = *(const uint4*)(smT + (size_t)o * C + c0 + part * 8);
            *(uint4*)&Bt[o * 40 + part * 8] = v;
        }
        __syncthreads();

        short8 af[4];
        #pragma unroll
        for (int mt = 0; mt < 4; ++mt)
            af[mt] = *(const short8*)&At[(mt * 16 + m) * 40 + kg * 8];
        short8 bfr[2];
        #pragma unroll
        for (int ot = 0; ot < 2; ++ot)
            bfr[ot] = *(const short8*)&Bt[((wave * 2 + ot) * 16 + m) * 40 + kg * 8];
        #pragma unroll
        for (int mt = 0; mt < 4; ++mt)
            #pragma unroll
            for (int ot = 0; ot < 2; ++ot)
                acc[mt][ot] = MFMA16(af[mt], bfr[ot], acc[mt][ot]);
        __syncthreads();
    }

    float* qbase = p.quad + (size_t)((lvl + 2) * 8 + n) * 128 * 16;
    #pragma unroll
    for (int ot = 0; ot < 2; ++ot) {
        float part = 0.f;
        #pragma unroll
        for (int mt = 0; mt < 4; ++mt)
            #pragma unroll
            for (int r = 0; r < 4; ++r) {
                float v = acc[mt][ot][r];
                part = fmaf(v, v, part);
            }
        part += __shfl_xor(part, 16);
        part += __shfl_xor(part, 32);
        if (lane < 16) {
            int o = (wave * 2 + ot) * 16 + lane;
            atomicAdd(qbase + (size_t)o * 16, part);
        }
    }
}

// ------------------------------------------------------------- head (split) --
__global__ __launch_bounds__(256) void hfc1_kernel(
    const float* __restrict__ quad, const float* __restrict__ w,
    const float* __restrict__ b, float* __restrict__ h1) {
    __shared__ float feat[640];
    __shared__ float stats[10];
    __shared__ float part[256];
    int blk = blockIdx.x;
    int n = blk >> 3, c8 = blk & 7;
    int t = threadIdx.x;
    for (int idx = t; idx < 640; idx += 256) {
        int L = idx >> 7, o = idx & 127;
        feat[idx] = quad[((size_t)(L * 8 + n) * 128 + o) * 16];
    }
    __syncthreads();
    int wv = t >> 6, lane = t & 63;
    for (int L = wv; L < 5; L += 4) {
        float a = feat[L * 128 + lane], c = feat[L * 128 + 64 + lane];
        float s = a + c;
        #pragma unroll
        for (int sh = 32; sh; sh >>= 1) s += __shfl_xor(s, sh);
        float mean = s * (1.f / 128.f);
        float d0 = a - mean, d1 = c - mean;
        float v = d0 * d0 + d1 * d1;
        #pragma unroll
        for (int sh = 32; sh; sh >>= 1) v += __shfl_xor(v, sh);
        if (lane == 0) {
            stats[L]     = mean;
            stats[5 + L] = 1.f / (sqrtf(v * (1.f / 127.f)) + 1e-8f);
        }
    }
    __syncthreads();
    for (int idx = t; idx < 640; idx += 256) {
        int L = idx >> 7;
        feat[idx] = (feat[idx] - stats[L]) * stats[5 + L];
    }
    __syncthreads();

    float acc = 0.f;
    const float* wc = w + c8 * 64 + lane;
    int k0 = wv * 160;
    #pragma unroll 8
    for (int k = k0; k < k0 + 160; ++k) acc = fmaf(feat[k], wc[(size_t)k * 512], acc);
    part[t] = acc;
    __syncthreads();
    if (t < 64) {
        float r = part[t] + part[t + 64] + part[t + 128] + part[t + 192];
        h1[(size_t)n * 512 + c8 * 64 + t] = r + b[c8 * 64 + t];
    }
}

__device__ __forceinline__ void norm_leaky_512(float* buf, float* red, int t) {
    float a = buf[t], c = buf[t + 256];
    float s = a + c;
    #pragma unroll
    for (int sh = 32; sh; sh >>= 1) s += __shfl_xor(s, sh);
    if ((t & 63) == 0) red[t >> 6] = s;
    __syncthreads();
    float mean = (red[0] + red[1] + red[2] + red[3]) * (1.f / 512.f);
    float d0 = a - mean, d1 = c - mean;
    float v = d0 * d0 + d1 * d1;
    #pragma unroll
    for (int sh = 32; sh; sh >>= 1) v += __shfl_xor(v, sh);
    __syncthreads();
    if ((t & 63) == 0) red[t >> 6] = v;
    __syncthreads();
    float inv = 1.f / (sqrtf((red[0] + red[1] + red[2] + red[3]) * (1.f / 511.f)) + 1e-8f);
    float n0 = d0 * inv, n1 = d1 * inv;
    buf[t]       = n0 > 0.f ? n0 : 0.01f * n0;
    buf[t + 256] = n1 > 0.f ? n1 : 0.01f * n1;
    __syncthreads();
}

__global__ __launch_bounds__(256) void hfc2_kernel(
    const float* __restrict__ h1, const float* __restrict__ w,
    const float* __restrict__ b, float* __restrict__ h2) {
    __shared__ float buf[512];
    __shared__ float red[4];
    __shared__ float part[256];
    int blk = blockIdx.x;
    int n = blk >> 3, c8 = blk & 7;
    int t = threadIdx.x;
    buf[t]       = h1[(size_t)n * 512 + t];
    buf[t + 256] = h1[(size_t)n * 512 + t + 256];
    __syncthreads();
    norm_leaky_512(buf, red, t);
    int wv = t >> 6, lane = t & 63;
    float acc = 0.f;
    const float* wc = w + c8 * 64 + lane;
    int k0 = wv * 128;
    #pragma unroll 8
    for (int k = k0; k < k0 + 128; ++k) acc = fmaf(buf[k], wc[(size_t)k * 512], acc);
    part[t] = acc;
    __syncthreads();
    if (t < 64) {
        float r = part[t] + part[t + 64] + part[t + 128] + part[t + 192];
        h2[(size_t)n * 512 + c8 * 64 + t] = r + b[c8 * 64 + t];
    }
}

__global__ __launch_bounds__(256) void hfc3_kernel(
    const float* __restrict__ h2, const float* __restrict__ w,
    const float* __restrict__ b, float* __restrict__ out) {
    __shared__ float buf[512];
    __shared__ float red[4];
    __shared__ float part[256];
    int blk = blockIdx.x;
    int n = blk >> 1, c2 = blk & 1;
    int t = threadIdx.x;
    buf[t]       = h2[(size_t)n * 512 + t];
    buf[t + 256] = h2[(size_t)n * 512 + t + 256];
    __syncthreads();
    norm_leaky_512(buf, red, t);
    int wv = t >> 6, lane = t & 63;
    float acc = 0.f;
    const float* wc = w + c2 * 64 + lane;
    int k0 = wv * 128;
    #pragma unroll 8
    for (int k = k0; k < k0 + 128; ++k) acc = fmaf(buf[k], wc[(size_t)k * 128], acc);
    part[t] = acc;
    __syncthreads();
    if (t < 64) {
        out[(size_t)n * 128 + c2 * 64 + t] =
            part[t] + part[t + 64] + part[t + 128] + part[t + 192] + b[c2 * 64 + t];
    }
}

// ----------------------------------------------------------------- launch ----
extern "C" void kernel_launch(void* const* d_in, const int* in_sizes, int n_in,
                              void* d_out, int out_size, void* d_ws, size_t ws_size,
                              hipStream_t stream) {
    static const int Cs[NLVL]   = {64, 128, 256, 512, 512};
    static const int RESs[NLVL] = {256, 128, 64, 32, 16};

    const float* x[NLVL];
    const float* w[NLVL];
    for (int i = 0; i < NLVL; ++i) {
        x[i] = (const float*)d_in[2 * i];
        w[i] = (const float*)d_in[2 * i + 1];
    }
    const float* fc1_w = (const float*)d_in[10];
    const float* fc1_b = (const float*)d_in[11];
    const float* fc2_w = (const float*)d_in[12];
    const float* fc2_b = (const float*)d_in[13];
    const float* fc3_w = (const float*)d_in[14];
    const float* fc3_b = (const float*)d_in[15];

    // workspace: smT (bf16) | quad padded fp32 | G0 | G1 | h1 | h2
    uint16_t* smT_base = (uint16_t*)d_ws;
    int smOff[NLVL];
    int off = 0;
    for (int i = 0; i < NLVL; ++i) { smOff[i] = off; off += Cs[i] * NQ; }
    size_t smBytes = (size_t)off * sizeof(uint16_t);
    float* quad = (float*)((char*)d_ws + smBytes);
    size_t quadFloats = (size_t)NLVL * 8 * NQ * 16;
    float* g0 = quad + quadFloats;
    float* g1 = g0 + (size_t)8 * 64 * 64;
    float* h1 = g1 + (size_t)8 * 128 * 128;
    float* h2 = h1 + (size_t)8 * 512;
    size_t zeroBytes = (quadFloats + (size_t)8 * 64 * 64 + (size_t)8 * 128 * 128) * sizeof(float);

    hipMemsetAsync(quad, 0, zeroBytes, stream);

    AParams ap;
    ap.x0 = x[0]; ap.x1 = x[1]; ap.g0 = g0; ap.g1 = g1;
    for (int i = 0; i < NLVL; ++i) {
        ap.w[i]   = w[i];
        ap.smT[i] = smT_base + smOff[i];
        ap.C[i]   = Cs[i];
    }
    // blocks: 512 L0-gram + 256 L1-gram + 80 softmax (8 (lvl,o)/block)
    gram_sm_kernel<<<848, 512, 0, stream>>>(ap);

    QSParams qp;
    int base = 0;
    for (int i = 0; i < 3; ++i) {
        int lvl = i + 2;
        qp.x[i]   = x[lvl];
        qp.smT[i] = smT_base + smOff[lvl];
        qp.C[i]   = Cs[lvl];
        qp.HW[i]  = RESs[lvl] * RESs[lvl];
        qp.blk_base[i] = base;
        base += (RESs[lvl] * RESs[lvl] / 64) * 8;
    }
    qp.quad = quad;
    qp.quad_blocks = base;                   // 672
    qp.g0 = g0; qp.g1 = g1;
    qp.smT0 = smT_base + smOff[0];
    qp.smT1 = smT_base + smOff[1];
    quad_sgs_kernel<<<base + 16, 256, 0, stream>>>(qp);

    hfc1_kernel<<<64, 256, 0, stream>>>(quad, fc1_w, fc1_b, h1);
    hfc2_kernel<<<64, 256, 0, stream>>>(h1, fc2_w, fc2_b, h2);
    hfc3_kernel<<<16, 256, 0, stream>>>(h2, fc3_w, fc3_b, (float*)d_out);
}